// Round 1
// 2326.778 us; speedup vs baseline: 3.3289x; 3.3289x over previous
//
#include <hip/hip_runtime.h>
#include <hip/hip_bf16.h>
#include <math.h>

#define B_    4
#define LSEQ  512
#define DE    1024
#define NH    16
#define DA    64
#define DMLP  4096
#define NV    32000
#define TOK   (B_ * LSEQ)
#define EPSF  1e-5f

typedef __attribute__((ext_vector_type(8))) short bf16x8;
typedef __attribute__((ext_vector_type(4))) float f32x4;

static __device__ __forceinline__ void gl_lds16(const void* g, void* l) {
    __builtin_amdgcn_global_load_lds((const __attribute__((address_space(1))) void*)g,
                                     (__attribute__((address_space(3))) void*)l, 16, 0, 0);
}
static __device__ __forceinline__ float bf2f(unsigned short u) {
    return __uint_as_float(((unsigned)u) << 16);
}
static __device__ __forceinline__ unsigned short f2bf(float f) {
    union { __hip_bfloat16 h; unsigned short s; } u;
    u.h = __float2bfloat16(f);
    return u.s;
}

// -------------------- fp32 -> bf16 convert (grid covers n/1024 blocks, 4 elems/thread) ----------
__global__ __launch_bounds__(256)
void convert_kernel(const float* __restrict__ src, unsigned short* __restrict__ dst)
{
    int i = (blockIdx.x * 256 + threadIdx.x) * 4;
    float4 v = *(const float4*)(src + i);
    ushort4 r;
    r.x = f2bf(v.x); r.y = f2bf(v.y); r.z = f2bf(v.z); r.w = f2bf(v.w);
    *(ushort4*)(dst + i) = r;
}

// -------------------- pack q/k/v biases into one 3072-float buffer -----------------------------
__global__ __launch_bounds__(256)
void pack_qkv_bias(const float* __restrict__ bq, const float* __restrict__ bk,
                   const float* __restrict__ bv, float* __restrict__ pb)
{
    int t = blockIdx.x * 256 + threadIdx.x;       // 0..3071
    float v = (t < 1024) ? bq[t] : (t < 2048) ? bk[t - 1024] : bv[t - 2048];
    pb[t] = v;
}

// -------------------- embedding: fp32 + bf16 outputs -------------------------------------------
__global__ __launch_bounds__(256)
void embed_kernel(const int* __restrict__ ids, const float* __restrict__ We,
                  const float* __restrict__ Wp, float* __restrict__ outf,
                  unsigned short* __restrict__ outb)
{
    int tk = blockIdx.x;
    int l  = tk & (LSEQ - 1);
    int idx = ids[tk];
    int d = threadIdx.x * 4;
    float4 a = *(const float4*)(We + (size_t)idx * DE + d);
    float4 b = *(const float4*)(Wp + (size_t)l * DE + d);
    float4 r; r.x = a.x + b.x; r.y = a.y + b.y; r.z = a.z + b.z; r.w = a.w + b.w;
    *(float4*)(outf + (size_t)tk * DE + d) = r;
    ushort4 rb; rb.x = f2bf(r.x); rb.y = f2bf(r.y); rb.z = f2bf(r.z); rb.w = f2bf(r.w);
    *(ushort4*)(outb + (size_t)tk * DE + d) = rb;
}

// -------------------- MFMA bf16 NT GEMM: C[m,n] = sum_k A[m,k]*W[n,k] ---------------------------
// A (TOK,K) bf16 row-major, W (N,K) bf16 row-major. 128x128 tile, BK=32, 4 waves (2x2 of 64x64).
// Output: bf16 (Cb) or fp32 (Cf) with row stride ldC; optional fp32 bias[n], resid[m*ldC+n], relu.
__global__ __launch_bounds__(256)
void gemm_bf16(const unsigned short* __restrict__ A, const unsigned short* __restrict__ W,
               const float* __restrict__ bias, const float* __restrict__ resid,
               float* __restrict__ Cf, unsigned short* __restrict__ Cb,
               int ldC, int K, int relu)
{
    __shared__ unsigned short Als[128 * 32];
    __shared__ unsigned short Wls[128 * 32];
    const int tid  = threadIdx.x;
    const int bm   = blockIdx.x << 7;           // m-tiles fastest: consecutive blocks share W tile
    const int bn   = blockIdx.y << 7;
    const int lane = tid & 63, wv = tid >> 6;
    const int wm   = (wv & 1) << 6, wn = (wv >> 1) << 6;
    const int fr   = lane & 15;                 // row-in-16 for frags, col for C
    const int fk   = (lane >> 4) << 3;          // k-offset for frags
    const int cr   = (lane >> 4) << 2;          // row base for C

    const unsigned short* Ag = A + (size_t)(bm + (tid >> 2)) * K + ((tid & 3) << 3);
    const unsigned short* Wg = W + (size_t)(bn + (tid >> 2)) * K + ((tid & 3) << 3);
    unsigned short* Al0 = Als + (tid << 3);
    unsigned short* Wl0 = Wls + (tid << 3);

    f32x4 acc[4][4];
    #pragma unroll
    for (int i = 0; i < 4; ++i)
        #pragma unroll
        for (int j = 0; j < 4; ++j) acc[i][j] = (f32x4){0.f, 0.f, 0.f, 0.f};

    for (int k0 = 0; k0 < K; k0 += 32) {
        gl_lds16(Ag + k0,                 Al0);
        gl_lds16(Ag + (size_t)64 * K + k0, Al0 + 2048);
        gl_lds16(Wg + k0,                 Wl0);
        gl_lds16(Wg + (size_t)64 * K + k0, Wl0 + 2048);
        __syncthreads();
        bf16x8 af[4], wf[4];
        #pragma unroll
        for (int i = 0; i < 4; ++i) af[i] = *(const bf16x8*)&Als[(wm + i * 16 + fr) * 32 + fk];
        #pragma unroll
        for (int j = 0; j < 4; ++j) wf[j] = *(const bf16x8*)&Wls[(wn + j * 16 + fr) * 32 + fk];
        #pragma unroll
        for (int i = 0; i < 4; ++i)
            #pragma unroll
            for (int j = 0; j < 4; ++j)
                acc[i][j] = __builtin_amdgcn_mfma_f32_16x16x32_bf16(af[i], wf[j], acc[i][j], 0, 0, 0);
        __syncthreads();
    }

    #pragma unroll
    for (int i = 0; i < 4; ++i) {
        #pragma unroll
        for (int j = 0; j < 4; ++j) {
            const int n = bn + wn + j * 16 + fr;
            const float bs = bias ? bias[n] : 0.0f;
            #pragma unroll
            for (int r = 0; r < 4; ++r) {
                const int m = bm + wm + i * 16 + cr + r;
                float v = acc[i][j][r] + bs;
                if (resid) v += resid[(size_t)m * ldC + n];
                if (relu)  v = fmaxf(v, 0.0f);
                if (Cb) Cb[(size_t)m * ldC + n] = f2bf(v);
                else    Cf[(size_t)m * ldC + n] = v;
            }
        }
    }
}

// -------------------- unembed: M = vocab (Wu fp32, converted in-kernel), N = tokens (Xb bf16) ---
// out[(b*NV + v)*LSEQ + lx] = dot(Wu[v], X[b,lx])   (coalesced stores along lx)
__global__ __launch_bounds__(256)
void unembed_kernel(const float* __restrict__ Wu, const unsigned short* __restrict__ Xb,
                    float* __restrict__ out)
{
    __shared__ float          Als[128 * 32];   // Wu tile fp32 (16 KB)
    __shared__ unsigned short Bls[128 * 32];   // X tile bf16 (8 KB)
    const int tid  = threadIdx.x;
    const int bm   = blockIdx.y << 7;          // vocab tile
    const int bn   = blockIdx.x << 7;          // token tile (fastest -> Wu L2 reuse)
    const int lane = tid & 63, wv = tid >> 6;
    const int wm   = (wv & 1) << 6, wn = (wv >> 1) << 6;
    const int fr   = lane & 15;
    const int fk   = (lane >> 4) << 3;
    const int cr   = (lane >> 4) << 2;

    const float* Ag = Wu + (size_t)(bm + (tid >> 3)) * DE + ((tid & 7) << 2);
    const unsigned short* Bg = Xb + (size_t)(bn + (tid >> 2)) * DE + ((tid & 3) << 3);
    float* Al0 = Als + (tid << 2);
    unsigned short* Bl0 = Bls + (tid << 3);

    f32x4 acc[4][4];
    #pragma unroll
    for (int i = 0; i < 4; ++i)
        #pragma unroll
        for (int j = 0; j < 4; ++j) acc[i][j] = (f32x4){0.f, 0.f, 0.f, 0.f};

    for (int k0 = 0; k0 < DE; k0 += 32) {
        #pragma unroll
        for (int q = 0; q < 4; ++q)
            gl_lds16(Ag + (size_t)q * 32 * DE + k0, Al0 + q * 1024);
        gl_lds16(Bg + k0,                  Bl0);
        gl_lds16(Bg + (size_t)64 * DE + k0, Bl0 + 2048);
        __syncthreads();
        bf16x8 af[4], bf[4];
        #pragma unroll
        for (int i = 0; i < 4; ++i) {
            const float* ap = &Als[(wm + i * 16 + fr) * 32 + fk];
            f32x4 u0 = *(const f32x4*)ap;
            f32x4 u1 = *(const f32x4*)(ap + 4);
            bf16x8 t;
            t[0] = (short)f2bf(u0[0]); t[1] = (short)f2bf(u0[1]);
            t[2] = (short)f2bf(u0[2]); t[3] = (short)f2bf(u0[3]);
            t[4] = (short)f2bf(u1[0]); t[5] = (short)f2bf(u1[1]);
            t[6] = (short)f2bf(u1[2]); t[7] = (short)f2bf(u1[3]);
            af[i] = t;
        }
        #pragma unroll
        for (int j = 0; j < 4; ++j) bf[j] = *(const bf16x8*)&Bls[(wn + j * 16 + fr) * 32 + fk];
        #pragma unroll
        for (int i = 0; i < 4; ++i)
            #pragma unroll
            for (int j = 0; j < 4; ++j)
                acc[i][j] = __builtin_amdgcn_mfma_f32_16x16x32_bf16(af[i], bf[j], acc[i][j], 0, 0, 0);
        __syncthreads();
    }

    #pragma unroll
    for (int i = 0; i < 4; ++i) {
        #pragma unroll
        for (int j = 0; j < 4; ++j) {
            const int tok = bn + wn + j * 16 + fr;
            const int b2  = tok >> 9;
            const int lx  = tok & (LSEQ - 1);
            #pragma unroll
            for (int r = 0; r < 4; ++r) {
                const int v = bm + wm + i * 16 + cr + r;
                out[((size_t)b2 * NV + v) * LSEQ + lx] = acc[i][j][r];
            }
        }
    }
}

// -------------------- flash attention (MFMA) on packed bf16 QKV (2048 x 3072: [q|k|v]) ----------
// Block = 4 waves, one (b,h), one 128-query tile. K-tiles of 128 keys, online softmax.
// S-phase: S[key,q] = K·Q^T via mfma (keys=rows so per-query reduce = shfl_xor 16/32 + partner).
// P round-trips through LDS (bf16, padded), V staged transposed; PV gives O[q,d] per wave (32 q).
__global__ __launch_bounds__(256)
void attn_kernel(const unsigned short* __restrict__ QKV, unsigned short* __restrict__ Ctx,
                 int causal)
{
    __shared__ unsigned short Qls[128 * 64];   // 16 KB, XOR-swizzled chunks
    __shared__ unsigned short Kls[128 * 64];   // 16 KB, XOR-swizzled chunks
    __shared__ unsigned short Vt[64 * 136];    // 17 KB, V^T [d][k], +8 pad
    __shared__ unsigned short Pq[128 * 136];   // 34 KB, P [q][k], +8 pad
    __shared__ float redm[4][64];
    __shared__ float reds[4][64];
    __shared__ float scl[128];

    const int qt   = blockIdx.x;
    const int h    = blockIdx.y;
    const int b    = blockIdx.z;
    const int tid  = threadIdx.x;
    const int lane = tid & 63;
    const int wv   = tid >> 6;
    const int g    = lane >> 4;
    const int fr   = lane & 15;
    const int wm   = (wv & 1) << 6;            // key sub-tile (S-phase)
    const int wn   = (wv >> 1) << 6;           // query sub-tile (S-phase)
    const int q0   = qt << 7;

    // ---- stage Q tile (swizzled: LDS chunk (row,a) holds global chunk a^(row&7)) ----
    const unsigned short* Qg = QKV + ((size_t)(b * LSEQ + q0)) * 3072 + h * 64;
    #pragma unroll
    for (int it = 0; it < 4; ++it) {
        const int ci = tid + it * 256;
        const int row = ci >> 3, c = (ci & 7) ^ (row & 7);
        gl_lds16(Qg + (size_t)row * 3072 + c * 8, Qls + ci * 8);
    }

    f32x4 acc_o[2][4];
    #pragma unroll
    for (int i = 0; i < 2; ++i)
        #pragma unroll
        for (int j = 0; j < 4; ++j) acc_o[i][j] = (f32x4){0.f, 0.f, 0.f, 0.f};
    float m_run[4], l_run[4];
    #pragma unroll
    for (int j = 0; j < 4; ++j) { m_run[j] = -INFINITY; l_run[j] = 0.0f; }

    const int ktmax = causal ? qt : 3;
    for (int kt = 0; kt <= ktmax; ++kt) {
        const int kz0 = kt << 7;
        __syncthreads();                                   // B1: Kls/Vt free for restage

        // ---- stage K tile (swizzled) ----
        const unsigned short* Kg = QKV + ((size_t)(b * LSEQ + kz0)) * 3072 + 1024 + h * 64;
        #pragma unroll
        for (int it = 0; it < 4; ++it) {
            const int ci = tid + it * 256;
            const int row = ci >> 3, c = (ci & 7) ^ (row & 7);
            gl_lds16(Kg + (size_t)row * 3072 + c * 8, Kls + ci * 8);
        }
        // ---- stage V transposed: Vt[d][k] = V[k][d]; thread handles 2 (k-pair, d-octet) slots ----
        bf16x8 v0[2], v1[2];
        const int kp = tid & 63;
        #pragma unroll
        for (int q2 = 0; q2 < 2; ++q2) {
            const int oc = (tid >> 6) + 4 * q2;
            const unsigned short* vg = QKV + ((size_t)(b * LSEQ + kz0 + 2 * kp)) * 3072
                                     + 2048 + h * 64 + oc * 8;
            v0[q2] = *(const bf16x8*)vg;
            v1[q2] = *(const bf16x8*)(vg + 3072);
        }
        #pragma unroll
        for (int q2 = 0; q2 < 2; ++q2) {
            const int oc = (tid >> 6) + 4 * q2;
            #pragma unroll
            for (int jj = 0; jj < 8; ++jj) {
                const unsigned int pk = (unsigned int)(unsigned short)v0[q2][jj]
                                      | ((unsigned int)(unsigned short)v1[q2][jj] << 16);
                *(unsigned int*)&Vt[(oc * 8 + jj) * 136 + 2 * kp] = pk;
            }
        }
        __syncthreads();                                   // B2: staging visible

        // ---- S = K·Q^T (per wave 64 keys x 64 queries) ----
        f32x4 acc_s[4][4];
        #pragma unroll
        for (int i = 0; i < 4; ++i)
            #pragma unroll
            for (int j = 0; j < 4; ++j) acc_s[i][j] = (f32x4){0.f, 0.f, 0.f, 0.f};
        #pragma unroll
        for (int kc = 0; kc < 2; ++kc) {
            bf16x8 kf[4], qf[4];
            #pragma unroll
            for (int i = 0; i < 4; ++i) {
                const int row = wm + i * 16 + fr;
                kf[i] = *(const bf16x8*)(Kls + row * 64 + (((kc * 4 + g) ^ (row & 7)) << 3));
            }
            #pragma unroll
            for (int j = 0; j < 4; ++j) {
                const int row = wn + j * 16 + fr;
                qf[j] = *(const bf16x8*)(Qls + row * 64 + (((kc * 4 + g) ^ (row & 7)) << 3));
            }
            #pragma unroll
            for (int i = 0; i < 4; ++i)
                #pragma unroll
                for (int j = 0; j < 4; ++j)
                    acc_s[i][j] = __builtin_amdgcn_mfma_f32_16x16x32_bf16(kf[i], qf[j], acc_s[i][j], 0, 0, 0);
        }

        // ---- scale + mask + per-query tile max ----
        float tmax[4];
        #pragma unroll
        for (int j = 0; j < 4; ++j) tmax[j] = -INFINITY;
        #pragma unroll
        for (int i = 0; i < 4; ++i)
            #pragma unroll
            for (int j = 0; j < 4; ++j)
                #pragma unroll
                for (int r = 0; r < 4; ++r) {
                    float s = acc_s[i][j][r] * 0.125f;
                    if (causal) {
                        const int key = kz0 + wm + i * 16 + 4 * g + r;
                        const int qq  = q0 + wn + j * 16 + fr;
                        if (key > qq) s = -INFINITY;
                    }
                    acc_s[i][j][r] = s;
                    tmax[j] = fmaxf(tmax[j], s);
                }
        #pragma unroll
        for (int j = 0; j < 4; ++j) {
            float v = tmax[j];
            v = fmaxf(v, __shfl_xor(v, 16));
            v = fmaxf(v, __shfl_xor(v, 32));
            tmax[j] = v;
        }
        if (lane < 16)
            #pragma unroll
            for (int j = 0; j < 4; ++j) redm[wv][j * 16 + fr] = tmax[j];
        __syncthreads();                                   // B3: partner max visible
        float mnew[4], tsum[4];
        #pragma unroll
        for (int j = 0; j < 4; ++j) {
            tmax[j] = fmaxf(tmax[j], redm[wv ^ 1][j * 16 + fr]);
            mnew[j] = fmaxf(m_run[j], tmax[j]);
            tsum[j] = 0.0f;
        }
        #pragma unroll
        for (int i = 0; i < 4; ++i)
            #pragma unroll
            for (int j = 0; j < 4; ++j)
                #pragma unroll
                for (int r = 0; r < 4; ++r) {
                    const float p = __expf(acc_s[i][j][r] - mnew[j]);
                    acc_s[i][j][r] = p;
                    tsum[j] += p;
                }
        #pragma unroll
        for (int j = 0; j < 4; ++j) {
            float v = tsum[j];
            v += __shfl_xor(v, 16);
            v += __shfl_xor(v, 32);
            tsum[j] = v;
        }
        if (lane < 16)
            #pragma unroll
            for (int j = 0; j < 4; ++j) reds[wv][j * 16 + fr] = tsum[j];
        __syncthreads();                                   // B4: partner sum visible
        float ef[4];
        #pragma unroll
        for (int j = 0; j < 4; ++j) {
            tsum[j] += reds[wv ^ 1][j * 16 + fr];
            ef[j] = __expf(m_run[j] - mnew[j]);
            l_run[j] = l_run[j] * ef[j] + tsum[j];
            m_run[j] = mnew[j];
        }
        if ((wv & 1) == 0 && lane < 16)
            #pragma unroll
            for (int j = 0; j < 4; ++j) scl[wn + j * 16 + fr] = ef[j];
        // ---- write P (bf16) to Pq[q][k] (r spans 4 consecutive k -> one b64) ----
        #pragma unroll
        for (int i = 0; i < 4; ++i)
            #pragma unroll
            for (int j = 0; j < 4; ++j) {
                short4 pk;
                pk.x = (short)f2bf(acc_s[i][j][0]);
                pk.y = (short)f2bf(acc_s[i][j][1]);
                pk.z = (short)f2bf(acc_s[i][j][2]);
                pk.w = (short)f2bf(acc_s[i][j][3]);
                *(short4*)&Pq[(wn + j * 16 + fr) * 136 + wm + i * 16 + 4 * g] = pk;
            }
        __syncthreads();                                   // B5: P + scl visible

        // ---- O rescale + PV (wave owns 32 q rows x 64 d) ----
        float f0[2][4];
        #pragma unroll
        for (int i = 0; i < 2; ++i)
            #pragma unroll
            for (int r = 0; r < 4; ++r) f0[i][r] = scl[32 * wv + 16 * i + 4 * g + r];
        #pragma unroll
        for (int i = 0; i < 2; ++i)
            #pragma unroll
            for (int j = 0; j < 4; ++j)
                #pragma unroll
                for (int r = 0; r < 4; ++r) acc_o[i][j][r] *= f0[i][r];
        #pragma unroll
        for (int kc = 0; kc < 4; ++kc) {
            bf16x8 pa[2], vb[4];
            #pragma unroll
            for (int i = 0; i < 2; ++i)
                pa[i] = *(const bf16x8*)(Pq + (32 * wv + 16 * i + fr) * 136 + kc * 32 + 8 * g);
            #pragma unroll
            for (int j = 0; j < 4; ++j)
                vb[j] = *(const bf16x8*)(Vt + (16 * j + fr) * 136 + kc * 32 + 8 * g);
            #pragma unroll
            for (int i = 0; i < 2; ++i)
                #pragma unroll
                for (int j = 0; j < 4; ++j)
                    acc_o[i][j] = __builtin_amdgcn_mfma_f32_16x16x32_bf16(pa[i], vb[j], acc_o[i][j], 0, 0, 0);
        }
    }

    // ---- epilogue: O /= l, store bf16 ----
    __syncthreads();
    if ((wv & 1) == 0 && lane < 16)
        #pragma unroll
        for (int j = 0; j < 4; ++j) scl[wn + j * 16 + fr] = 1.0f / l_run[j];
    __syncthreads();
    #pragma unroll
    for (int i = 0; i < 2; ++i) {
        #pragma unroll
        for (int r = 0; r < 4; ++r) {
            const int q  = q0 + 32 * wv + 16 * i + 4 * g + r;
            const float fl = scl[32 * wv + 16 * i + 4 * g + r];
            #pragma unroll
            for (int j = 0; j < 4; ++j) {
                const int d = 16 * j + fr;
                Ctx[((size_t)(b * LSEQ + q)) * DE + h * 64 + d] = f2bf(acc_o[i][j][r] * fl);
            }
        }
    }
}

// -------------------- layernorm over DE (ddof=1): fp32 in -> fp32 + bf16 out --------------------
__global__ __launch_bounds__(256)
void ln_kernel(const float* __restrict__ in, float* __restrict__ outf,
               unsigned short* __restrict__ outb,
               const float* __restrict__ g, const float* __restrict__ bb)
{
    __shared__ float red[256];
    const int tk  = blockIdx.x;
    const int tid = threadIdx.x;
    const float* xr = in + (size_t)tk * DE;
    const int d = tid * 4;
    float4 v = *(const float4*)(xr + d);

    red[tid] = v.x + v.y + v.z + v.w; __syncthreads();
    for (int st = 128; st > 0; st >>= 1) {
        if (tid < st) red[tid] += red[tid + st];
        __syncthreads();
    }
    const float mean = red[0] * (1.0f / DE);
    __syncthreads();

    float dx = v.x - mean, dy = v.y - mean, dz = v.z - mean, dw = v.w - mean;
    red[tid] = dx * dx + dy * dy + dz * dz + dw * dw;
    __syncthreads();
    for (int st = 128; st > 0; st >>= 1) {
        if (tid < st) red[tid] += red[tid + st];
        __syncthreads();
    }
    const float rstd = rsqrtf(red[0] * (1.0f / (DE - 1)) + EPSF);   // ddof=1

    float4 gg = *(const float4*)(g + d);
    float4 b4 = *(const float4*)(bb + d);
    float4 r;
    r.x = dx * rstd * gg.x + b4.x;
    r.y = dy * rstd * gg.y + b4.y;
    r.z = dz * rstd * gg.z + b4.z;
    r.w = dw * rstd * gg.w + b4.w;
    *(float4*)(outf + (size_t)tk * DE + d) = r;
    ushort4 rb; rb.x = f2bf(r.x); rb.y = f2bf(r.y); rb.z = f2bf(r.z); rb.w = f2bf(r.w);
    *(ushort4*)(outb + (size_t)tk * DE + d) = rb;
}

// -------------------- vocab softmax, 3-pass (out layout (b, v, l)) ------------------------------
#define VT1 50      // pass1 vocab tiles (640 v each)
__global__ __launch_bounds__(256)
void vsm_pass1(const float* __restrict__ out, float* __restrict__ Pm, float* __restrict__ Ps)
{
    __shared__ float sm[4][64], ss[4][64];
    const int tid = threadIdx.x, tx = tid & 63, ty = tid >> 6;
    const int l = blockIdx.x * 64 + tx, b = blockIdx.z, vt = blockIdx.y;
    const size_t base = ((size_t)b * NV + (size_t)vt * 640) * LSEQ + l;
    float m = -1e30f, s = 0.0f;
    for (int v = ty; v < 640; v += 4) {
        float w = out[base + (size_t)v * LSEQ];
        if (w > m) { s = s * __expf(m - w) + 1.0f; m = w; }
        else       { s += __expf(w - m); }
    }
    sm[ty][tx] = m; ss[ty][tx] = s;
    __syncthreads();
    if (ty == 0) {
        float M = sm[0][tx];
        #pragma unroll
        for (int q = 1; q < 4; ++q) M = fmaxf(M, sm[q][tx]);
        float S = 0.0f;
        #pragma unroll
        for (int q = 0; q < 4; ++q) S += ss[q][tx] * __expf(sm[q][tx] - M);
        const int tk = b * LSEQ + l;
        Pm[tk * VT1 + vt] = M;
        Ps[tk * VT1 + vt] = S;
    }
}

__global__ __launch_bounds__(256)
void vsm_pass2(const float* __restrict__ Pm, const float* __restrict__ Ps,
               float* __restrict__ Fm, float* __restrict__ Fr)
{
    const int tk = blockIdx.x * 256 + threadIdx.x;
    float M = -1e30f;
    for (int i = 0; i < VT1; ++i) M = fmaxf(M, Pm[tk * VT1 + i]);
    float S = 0.0f;
    for (int i = 0; i < VT1; ++i) S += Ps[tk * VT1 + i] * __expf(Pm[tk * VT1 + i] - M);
    Fm[tk] = M; Fr[tk] = 1.0f / S;
}

__global__ __launch_bounds__(256)
void vsm_pass3(float* __restrict__ out, const float* __restrict__ Fm, const float* __restrict__ Fr)
{
    const int tid = threadIdx.x, tx = tid & 63, ty = tid >> 6;
    const int l = blockIdx.x * 64 + tx, b = blockIdx.z;
    const int tk = b * LSEQ + l;
    const float M = Fm[tk], R = Fr[tk];
    const size_t base = ((size_t)b * NV + (size_t)blockIdx.y * 256) * LSEQ + l;
    for (int v = ty; v < 256; v += 4) {
        const size_t off = base + (size_t)v * LSEQ;
        out[off] = __expf(out[off] - M) * R;
    }
}

// ================================================================================================
extern "C" void kernel_launch(void* const* d_in, const int* in_sizes, int n_in,
                              void* d_out, int out_size, void* d_ws, size_t ws_size,
                              hipStream_t stream)
{
    (void)in_sizes; (void)n_in; (void)out_size; (void)ws_size;
    const int*   x  = (const int*)d_in[0];
    const int*   z  = (const int*)d_in[1];
    const float* We = (const float*)d_in[2];
    const float* Wp = (const float*)d_in[3];
    const float* Wu = (const float*)d_in[4];
    const float* encW[12]; for (int i = 0; i < 12; ++i) encW[i] = (const float*)d_in[5 + i];
    const float* encLN[4]; for (int i = 0; i < 4;  ++i) encLN[i] = (const float*)d_in[17 + i];
    const float* decW[12]; for (int i = 0; i < 12; ++i) decW[i] = (const float*)d_in[21 + i];
    const float* decLN[6]; for (int i = 0; i < 6;  ++i) decLN[i] = (const float*)d_in[33 + i];
    float* out = (float*)d_out;

    const size_t MB = 1024 * 1024;
    char* w = (char*)d_ws;
    float* Z            = (float*)(w + 0 * MB);          // 8 MB (reused for softmax partials)
    float* X            = (float*)(w + 8 * MB);          // 8 MB
    float* T            = (float*)(w + 16 * MB);         // 8 MB
    unsigned short* Zb  = (unsigned short*)(w + 24 * MB); // 4 MB
    unsigned short* Xb  = (unsigned short*)(w + 28 * MB); // 4 MB
    unsigned short* QKVb= (unsigned short*)(w + 32 * MB); // 12 MB (2048 x 3072)
    unsigned short* Cxb = (unsigned short*)(w + 44 * MB); // 4 MB
    unsigned short* Hb  = (unsigned short*)(w + 48 * MB); // 16 MB (2048 x 4096)
    unsigned short* Wqkvb = (unsigned short*)(w + 64 * MB); // 6 MB (3072 x 1024)
    unsigned short* Wob   = (unsigned short*)(w + 70 * MB); // 2 MB
    unsigned short* W1b   = (unsigned short*)(w + 72 * MB); // 8 MB
    unsigned short* W2b   = (unsigned short*)(w + 80 * MB); // 8 MB  -> 88 MB total
    float* pb = (float*)Hb;            // packed qkv bias; aliases Hb (dead until MLP1 writes it)
    float* Pm = Z;                     // softmax partials alias Z (dead after decoder loop)
    float* Ps = Z + (size_t)TOK * VT1;
    float* Fm = Z + (size_t)TOK * 2 * VT1;
    float* Fr = Fm + TOK;

    auto conv = [&](const float* s, unsigned short* d, int n) {
        convert_kernel<<<n / 1024, 256, 0, stream>>>(s, d);
    };
    auto gemm = [&](const unsigned short* A, const unsigned short* Wt, const float* bias,
                    const float* resid, float* Cf, unsigned short* Cb, int ldC, int ntiles,
                    int K, int relu) {
        gemm_bf16<<<dim3(TOK / 128, ntiles), 256, 0, stream>>>(A, Wt, bias, resid, Cf, Cb,
                                                               ldC, K, relu);
    };
    auto lnorm = [&](const float* in, float* of, unsigned short* ob,
                     const float* g, const float* bb) {
        ln_kernel<<<TOK, 256, 0, stream>>>(in, of, ob, g, bb);
    };
    auto attn = [&](unsigned short* ctx, int causal) {
        attn_kernel<<<dim3(LSEQ / 128, NH, B_), 256, 0, stream>>>(QKVb, ctx, causal);
    };

    // ---------------- encoder ----------------
    embed_kernel<<<TOK, 256, 0, stream>>>(z, We, Wp, Z, Zb);
    for (int l = 0; l < 2; ++l) {
        const size_t wo  = (size_t)l * DE * DE;
        const size_t bo  = (size_t)l * DE;
        const size_t w1o = (size_t)l * DMLP * DE;
        const size_t b1o = (size_t)l * DMLP;
        conv(encW[0] + wo, Wqkvb,                 DE * DE);
        conv(encW[2] + wo, Wqkvb + DE * DE,       DE * DE);
        conv(encW[4] + wo, Wqkvb + 2 * DE * DE,   DE * DE);
        pack_qkv_bias<<<12, 256, 0, stream>>>(encW[1] + bo, encW[3] + bo, encW[5] + bo, pb);
        gemm(Zb, Wqkvb, pb, nullptr, nullptr, QKVb, 3072, 24, DE, 0);
        attn(Cxb, 0);
        conv(encW[6] + wo, Wob, DE * DE);
        gemm(Cxb, Wob, encW[7] + bo, Z, T, nullptr, DE, 8, DE, 0);
        lnorm(T, Z, Zb, encLN[0] + bo, encLN[1] + bo);
        conv(encW[8] + w1o, W1b, DMLP * DE);
        gemm(Zb, W1b, encW[9] + b1o, nullptr, nullptr, Hb, DMLP, 32, DE, 1);
        conv(encW[10] + w1o, W2b, DMLP * DE);
        gemm(Hb, W2b, encW[11] + bo, Z, T, nullptr, DE, 8, DMLP, 0);
        lnorm(T, Z, Zb, encLN[2] + bo, encLN[3] + bo);
    }

    // ---------------- decoder ----------------
    embed_kernel<<<TOK, 256, 0, stream>>>(x, We, Wp, X, Xb);
    for (int l = 0; l < 2; ++l) {
        const size_t wo  = (size_t)l * DE * DE;
        const size_t bo  = (size_t)l * DE;
        const size_t w1o = (size_t)l * DMLP * DE;
        const size_t b1o = (size_t)l * DMLP;
        conv(decW[0] + wo, Wqkvb,               DE * DE);
        conv(decW[2] + wo, Wqkvb + DE * DE,     DE * DE);
        conv(decW[4] + wo, Wqkvb + 2 * DE * DE, DE * DE);
        pack_qkv_bias<<<12, 256, 0, stream>>>(decW[1] + bo, decW[3] + bo, decW[5] + bo, pb);
        conv(decW[6] + wo, Wob, DE * DE);
        // self-attention (causal)
        gemm(Xb, Wqkvb, pb, nullptr, nullptr, QKVb, 3072, 24, DE, 0);
        attn(Cxb, 1);
        gemm(Cxb, Wob, decW[7] + bo, X, T, nullptr, DE, 8, DE, 0);
        lnorm(T, X, Xb, decLN[0] + bo, decLN[1] + bo);
        // cross-attention: Q from X, K/V from encoder Z (same weights)
        gemm(Xb, Wqkvb, pb, nullptr, nullptr, QKVb, 3072, 8, DE, 0);                     // Q
        gemm(Zb, Wqkvb + DE * DE, pb + 1024, nullptr, nullptr, QKVb + 1024, 3072, 16, DE, 0); // K,V
        attn(Cxb, 0);
        gemm(Cxb, Wob, decW[7] + bo, X, T, nullptr, DE, 8, DE, 0);
        lnorm(T, X, Xb, decLN[2] + bo, decLN[3] + bo);
        // MLP
        conv(decW[8] + w1o, W1b, DMLP * DE);
        gemm(Xb, W1b, decW[9] + b1o, nullptr, nullptr, Hb, DMLP, 32, DE, 1);
        conv(decW[10] + w1o, W2b, DMLP * DE);
        gemm(Hb, W2b, decW[11] + bo, X, T, nullptr, DE, 8, DMLP, 0);
        lnorm(T, X, Xb, decLN[4] + bo, decLN[5] + bo);
    }

    // ---------------- unembed + vocab softmax ----------------
    unembed_kernel<<<dim3(TOK / 128, NV / 128), 256, 0, stream>>>(Wu, Xb, out);
    vsm_pass1<<<dim3(LSEQ / 64, VT1, B_), 256, 0, stream>>>(out, Pm, Ps);
    vsm_pass2<<<TOK / 256, 256, 0, stream>>>(Pm, Ps, Fm, Fr);
    vsm_pass3<<<dim3(LSEQ / 64, NV / 256, B_), 256, 0, stream>>>(out, Fm, Fr);
}

// Round 2
// 2310.790 us; speedup vs baseline: 3.3519x; 1.0069x over previous
//
#include <hip/hip_runtime.h>
#include <hip/hip_bf16.h>
#include <math.h>

#define B_    4
#define LSEQ  512
#define DE    1024
#define NH    16
#define DA    64
#define DMLP  4096
#define NV    32000
#define TOK   (B_ * LSEQ)
#define EPSF  1e-5f
#define NVT   250     // vocab tiles of 128 (fused softmax partials)

typedef __attribute__((ext_vector_type(8))) short bf16x8;
typedef __attribute__((ext_vector_type(4))) float f32x4;

static __device__ __forceinline__ void gl_lds16(const void* g, void* l) {
    __builtin_amdgcn_global_load_lds((const __attribute__((address_space(1))) void*)g,
                                     (__attribute__((address_space(3))) void*)l, 16, 0, 0);
}
static __device__ __forceinline__ float bf2f(unsigned short u) {
    return __uint_as_float(((unsigned)u) << 16);
}
static __device__ __forceinline__ unsigned short f2bf(float f) {
    union { __hip_bfloat16 h; unsigned short s; } u;
    u.h = __float2bfloat16(f);
    return u.s;
}

// -------------------- fp32 -> bf16 convert (grid covers n/1024 blocks, 4 elems/thread) ----------
__global__ __launch_bounds__(256)
void convert_kernel(const float* __restrict__ src, unsigned short* __restrict__ dst)
{
    int i = (blockIdx.x * 256 + threadIdx.x) * 4;
    float4 v = *(const float4*)(src + i);
    ushort4 r;
    r.x = f2bf(v.x); r.y = f2bf(v.y); r.z = f2bf(v.z); r.w = f2bf(v.w);
    *(ushort4*)(dst + i) = r;
}

// -------------------- 3-source convert (q,k,v weight mats, each DE*DE floats) -------------------
__global__ __launch_bounds__(256)
void convert3_kernel(const float* __restrict__ s0, const float* __restrict__ s1,
                     const float* __restrict__ s2, unsigned short* __restrict__ dst)
{
    int i = (blockIdx.x * 256 + threadIdx.x) * 4;
    const float* s = (i < DE * DE) ? s0 : (i < 2 * DE * DE) ? s1 : s2;
    float4 v = *(const float4*)(s + (i & (DE * DE - 1)));
    ushort4 r;
    r.x = f2bf(v.x); r.y = f2bf(v.y); r.z = f2bf(v.z); r.w = f2bf(v.w);
    *(ushort4*)(dst + i) = r;
}

// -------------------- pack q/k/v biases into one 3072-float buffer -----------------------------
__global__ __launch_bounds__(256)
void pack_qkv_bias(const float* __restrict__ bq, const float* __restrict__ bk,
                   const float* __restrict__ bv, float* __restrict__ pb)
{
    int t = blockIdx.x * 256 + threadIdx.x;       // 0..3071
    float v = (t < 1024) ? bq[t] : (t < 2048) ? bk[t - 1024] : bv[t - 2048];
    pb[t] = v;
}

// -------------------- embedding: fp32 + bf16 outputs -------------------------------------------
__global__ __launch_bounds__(256)
void embed_kernel(const int* __restrict__ ids, const float* __restrict__ We,
                  const float* __restrict__ Wp, float* __restrict__ outf,
                  unsigned short* __restrict__ outb)
{
    int tk = blockIdx.x;
    int l  = tk & (LSEQ - 1);
    int idx = ids[tk];
    int d = threadIdx.x * 4;
    float4 a = *(const float4*)(We + (size_t)idx * DE + d);
    float4 b = *(const float4*)(Wp + (size_t)l * DE + d);
    float4 r; r.x = a.x + b.x; r.y = a.y + b.y; r.z = a.z + b.z; r.w = a.w + b.w;
    *(float4*)(outf + (size_t)tk * DE + d) = r;
    ushort4 rb; rb.x = f2bf(r.x); rb.y = f2bf(r.y); rb.z = f2bf(r.z); rb.w = f2bf(r.w);
    *(ushort4*)(outb + (size_t)tk * DE + d) = rb;
}

// -------------------- MFMA bf16 NT GEMM: C[m,n] = sum_k A[m,k]*W[n,k] ---------------------------
// A (TOK,K) bf16 row-major, W (N,K) bf16 row-major. 128x128 tile, BK=32, 4 waves (2x2 of 64x64).
// XCD-chunked block swizzle: blocks sharing a W tile stay on one XCD's L2.
__global__ __launch_bounds__(256)
void gemm_bf16(const unsigned short* __restrict__ A, const unsigned short* __restrict__ W,
               const float* __restrict__ bias, const float* __restrict__ resid,
               float* __restrict__ Cf, unsigned short* __restrict__ Cb,
               int ldC, int K, int relu)
{
    __shared__ unsigned short Als[128 * 32];
    __shared__ unsigned short Wls[128 * 32];
    const int tid  = threadIdx.x;
    const int nwg  = gridDim.y << 4;                    // gridDim.x == 16 (token tiles)
    const int lid  = (blockIdx.y << 4) + blockIdx.x;
    const int wg   = (lid & 7) * (nwg >> 3) + (lid >> 3);
    const int bm   = (wg & 15) << 7;                    // token tile (fastest within chunk)
    const int bn   = (wg >> 4) << 7;                    // W tile (shared by 16 consecutive wg)
    const int lane = tid & 63, wv = tid >> 6;
    const int wm   = (wv & 1) << 6, wn = (wv >> 1) << 6;
    const int fr   = lane & 15;                 // row-in-16 for frags, col for C
    const int fk   = (lane >> 4) << 3;          // k-offset for frags
    const int cr   = (lane >> 4) << 2;          // row base for C

    const unsigned short* Ag = A + (size_t)(bm + (tid >> 2)) * K + ((tid & 3) << 3);
    const unsigned short* Wg = W + (size_t)(bn + (tid >> 2)) * K + ((tid & 3) << 3);
    unsigned short* Al0 = Als + (tid << 3);
    unsigned short* Wl0 = Wls + (tid << 3);

    f32x4 acc[4][4];
    #pragma unroll
    for (int i = 0; i < 4; ++i)
        #pragma unroll
        for (int j = 0; j < 4; ++j) acc[i][j] = (f32x4){0.f, 0.f, 0.f, 0.f};

    for (int k0 = 0; k0 < K; k0 += 32) {
        gl_lds16(Ag + k0,                 Al0);
        gl_lds16(Ag + (size_t)64 * K + k0, Al0 + 2048);
        gl_lds16(Wg + k0,                 Wl0);
        gl_lds16(Wg + (size_t)64 * K + k0, Wl0 + 2048);
        __syncthreads();
        bf16x8 af[4], wf[4];
        #pragma unroll
        for (int i = 0; i < 4; ++i) af[i] = *(const bf16x8*)&Als[(wm + i * 16 + fr) * 32 + fk];
        #pragma unroll
        for (int j = 0; j < 4; ++j) wf[j] = *(const bf16x8*)&Wls[(wn + j * 16 + fr) * 32 + fk];
        #pragma unroll
        for (int i = 0; i < 4; ++i)
            #pragma unroll
            for (int j = 0; j < 4; ++j)
                acc[i][j] = __builtin_amdgcn_mfma_f32_16x16x32_bf16(af[i], wf[j], acc[i][j], 0, 0, 0);
        __syncthreads();
    }

    #pragma unroll
    for (int i = 0; i < 4; ++i) {
        #pragma unroll
        for (int j = 0; j < 4; ++j) {
            const int n = bn + wn + j * 16 + fr;
            const float bs = bias ? bias[n] : 0.0f;
            #pragma unroll
            for (int r = 0; r < 4; ++r) {
                const int m = bm + wm + i * 16 + cr + r;
                float v = acc[i][j][r] + bs;
                if (resid) v += resid[(size_t)m * ldC + n];
                if (relu)  v = fmaxf(v, 0.0f);
                if (Cb) Cb[(size_t)m * ldC + n] = f2bf(v);
                else    Cf[(size_t)m * ldC + n] = v;
            }
        }
    }
}

// -------------------- unembed: M = vocab, N = tokens, K = DE ------------------------------------
// Wu fp32 reg-staged -> bf16 XOR-swizzled LDS (slot = chunk ^ ((row>>1)&3), bank-quad uniform).
// Fused vocab-softmax pass1: per-block (max, sumexp) partials over its 128 vocab rows per token.
__global__ __launch_bounds__(256)
void unembed_kernel(const float* __restrict__ Wu, const unsigned short* __restrict__ Xb,
                    float* __restrict__ out, float* __restrict__ Pm, float* __restrict__ Ps)
{
    __shared__ unsigned short Als[128 * 32];   // Wu tile bf16, swizzled (8 KB)
    __shared__ unsigned short Bls[128 * 32];   // X tile bf16, linear (8 KB)
    __shared__ float redm[4][64], reds[4][64];
    const int tid  = threadIdx.x;
    const int lid  = (blockIdx.y << 4) + blockIdx.x;      // grid (16, 250)
    const int wg   = (lid & 7) * ((16 * NVT) >> 3) + (lid >> 3);
    const int vt   = wg >> 4;                  // vocab tile (shared by 16 consecutive wg)
    const int bm   = vt << 7;                  // vocab base
    const int bn   = (wg & 15) << 7;           // token base
    const int lane = tid & 63, wv = tid >> 6;
    const int wm   = (wv & 1) << 6, wn = (wv >> 1) << 6;
    const int fr   = lane & 15;
    const int g    = lane >> 4;
    const int fk   = g << 3;
    const int cr   = g << 2;

    // staging: thread covers row srow, chunks {sch, sch+1} (chunk = 8 bf16 = 16 B)
    const int srow = tid >> 1;
    const int sch  = (tid & 1) << 1;
    const float* Ag = Wu + (size_t)(bm + srow) * DE + (sch << 3);
    const int sl0 = ((sch)     ^ ((srow >> 1) & 3)) << 3;
    const int sl1 = ((sch + 1) ^ ((srow >> 1) & 3)) << 3;
    unsigned short* Arow = Als + srow * 32;

    const unsigned short* Bg = Xb + (size_t)(bn + (tid >> 2)) * DE + ((tid & 3) << 3);
    unsigned short* Bl0 = Bls + (tid << 3);

    f32x4 acc[4][4];
    #pragma unroll
    for (int i = 0; i < 4; ++i)
        #pragma unroll
        for (int j = 0; j < 4; ++j) acc[i][j] = (f32x4){0.f, 0.f, 0.f, 0.f};

    for (int k0 = 0; k0 < DE; k0 += 32) {
        gl_lds16(Bg + k0,                  Bl0);
        gl_lds16(Bg + (size_t)64 * DE + k0, Bl0 + 2048);
        const float* ap = Ag + k0;
        f32x4 u0 = *(const f32x4*)(ap);
        f32x4 u1 = *(const f32x4*)(ap + 4);
        f32x4 u2 = *(const f32x4*)(ap + 8);
        f32x4 u3 = *(const f32x4*)(ap + 12);
        bf16x8 t0, t1;
        t0[0] = (short)f2bf(u0[0]); t0[1] = (short)f2bf(u0[1]);
        t0[2] = (short)f2bf(u0[2]); t0[3] = (short)f2bf(u0[3]);
        t0[4] = (short)f2bf(u1[0]); t0[5] = (short)f2bf(u1[1]);
        t0[6] = (short)f2bf(u1[2]); t0[7] = (short)f2bf(u1[3]);
        t1[0] = (short)f2bf(u2[0]); t1[1] = (short)f2bf(u2[1]);
        t1[2] = (short)f2bf(u2[2]); t1[3] = (short)f2bf(u2[3]);
        t1[4] = (short)f2bf(u3[0]); t1[5] = (short)f2bf(u3[1]);
        t1[6] = (short)f2bf(u3[2]); t1[7] = (short)f2bf(u3[3]);
        *(bf16x8*)(Arow + sl0) = t0;
        *(bf16x8*)(Arow + sl1) = t1;
        __syncthreads();
        bf16x8 af[4], bfg[4];
        #pragma unroll
        for (int i = 0; i < 4; ++i) {
            const int row = wm + i * 16 + fr;
            af[i] = *(const bf16x8*)&Als[row * 32 + ((g ^ ((row >> 1) & 3)) << 3)];
        }
        #pragma unroll
        for (int j = 0; j < 4; ++j) bfg[j] = *(const bf16x8*)&Bls[(wn + j * 16 + fr) * 32 + fk];
        #pragma unroll
        for (int i = 0; i < 4; ++i)
            #pragma unroll
            for (int j = 0; j < 4; ++j)
                acc[i][j] = __builtin_amdgcn_mfma_f32_16x16x32_bf16(af[i], bfg[j], acc[i][j], 0, 0, 0);
        __syncthreads();
    }

    // ---- store logits (layout (b, v, l)) ----
    #pragma unroll
    for (int i = 0; i < 4; ++i) {
        #pragma unroll
        for (int j = 0; j < 4; ++j) {
            const int tok = bn + wn + j * 16 + fr;
            const int b2  = tok >> 9;
            const int lx  = tok & (LSEQ - 1);
            #pragma unroll
            for (int r = 0; r < 4; ++r) {
                const int v = bm + wm + i * 16 + cr + r;
                out[((size_t)b2 * NV + v) * LSEQ + lx] = acc[i][j][r];
            }
        }
    }

    // ---- fused softmax pass1: per-(vt, token) max & sumexp over this block's 128 vocab ----
    float pmx[4], psm[4];
    #pragma unroll
    for (int j = 0; j < 4; ++j) {
        float m = acc[0][j][0];
        #pragma unroll
        for (int i = 0; i < 4; ++i)
            #pragma unroll
            for (int r = 0; r < 4; ++r) m = fmaxf(m, acc[i][j][r]);
        m = fmaxf(m, __shfl_xor(m, 16));
        m = fmaxf(m, __shfl_xor(m, 32));
        pmx[j] = m;
        float s = 0.0f;
        #pragma unroll
        for (int i = 0; i < 4; ++i)
            #pragma unroll
            for (int r = 0; r < 4; ++r) s += __expf(acc[i][j][r] - m);
        s += __shfl_xor(s, 16);
        s += __shfl_xor(s, 32);
        psm[j] = s;
    }
    if (lane < 16) {
        #pragma unroll
        for (int j = 0; j < 4; ++j) { redm[wv][j * 16 + fr] = pmx[j]; reds[wv][j * 16 + fr] = psm[j]; }
    }
    __syncthreads();
    if ((wv & 1) == 0 && lane < 16) {
        #pragma unroll
        for (int j = 0; j < 4; ++j) {
            const float mo = redm[wv ^ 1][j * 16 + fr];
            const float so = reds[wv ^ 1][j * 16 + fr];
            const float M  = fmaxf(pmx[j], mo);
            const float S  = psm[j] * __expf(pmx[j] - M) + so * __expf(mo - M);
            const int tok  = bn + wn + j * 16 + fr;
            Pm[(size_t)vt * TOK + tok] = M;
            Ps[(size_t)vt * TOK + tok] = S;
        }
    }
}

// -------------------- flash attention (MFMA) on packed bf16 QKV (2048 x 3072: [q|k|v]) ----------
__global__ __launch_bounds__(256)
void attn_kernel(const unsigned short* __restrict__ QKV, unsigned short* __restrict__ Ctx,
                 int causal)
{
    __shared__ unsigned short Qls[128 * 64];   // 16 KB, XOR-swizzled chunks
    __shared__ unsigned short Kls[128 * 64];   // 16 KB, XOR-swizzled chunks
    __shared__ unsigned short Vt[64 * 136];    // 17 KB, V^T [d][k], +8 pad
    __shared__ unsigned short Pq[128 * 136];   // 34 KB, P [q][k], +8 pad
    __shared__ float redm[4][64];
    __shared__ float reds[4][64];
    __shared__ float scl[128];

    // XCD-chunked remap: all q-tiles of a (b,h) (shared K/V) on one XCD
    const int lid = (blockIdx.z * 16 + blockIdx.y) * 4 + blockIdx.x;
    const int wg  = (lid & 7) * 32 + (lid >> 3);
    const int qt  = wg & 3;
    const int h   = (wg >> 2) & 15;
    const int b   = wg >> 6;
    const int tid  = threadIdx.x;
    const int lane = tid & 63;
    const int wv   = tid >> 6;
    const int g    = lane >> 4;
    const int fr   = lane & 15;
    const int wm   = (wv & 1) << 6;            // key sub-tile (S-phase)
    const int wn   = (wv >> 1) << 6;           // query sub-tile (S-phase)
    const int q0   = qt << 7;

    // ---- stage Q tile (swizzled: LDS chunk (row,a) holds global chunk a^(row&7)) ----
    const unsigned short* Qg = QKV + ((size_t)(b * LSEQ + q0)) * 3072 + h * 64;
    #pragma unroll
    for (int it = 0; it < 4; ++it) {
        const int ci = tid + it * 256;
        const int row = ci >> 3, c = (ci & 7) ^ (row & 7);
        gl_lds16(Qg + (size_t)row * 3072 + c * 8, Qls + ci * 8);
    }

    f32x4 acc_o[2][4];
    #pragma unroll
    for (int i = 0; i < 2; ++i)
        #pragma unroll
        for (int j = 0; j < 4; ++j) acc_o[i][j] = (f32x4){0.f, 0.f, 0.f, 0.f};
    float m_run[4], l_run[4];
    #pragma unroll
    for (int j = 0; j < 4; ++j) { m_run[j] = -INFINITY; l_run[j] = 0.0f; }

    const int ktmax = causal ? qt : 3;
    for (int kt = 0; kt <= ktmax; ++kt) {
        const int kz0 = kt << 7;
        __syncthreads();                                   // B1: Kls/Vt free for restage

        // ---- stage K tile (swizzled) ----
        const unsigned short* Kg = QKV + ((size_t)(b * LSEQ + kz0)) * 3072 + 1024 + h * 64;
        #pragma unroll
        for (int it = 0; it < 4; ++it) {
            const int ci = tid + it * 256;
            const int row = ci >> 3, c = (ci & 7) ^ (row & 7);
            gl_lds16(Kg + (size_t)row * 3072 + c * 8, Kls + ci * 8);
        }
        // ---- stage V transposed: Vt[d][k] = V[k][d]; thread handles 2 (k-pair, d-octet) slots ----
        bf16x8 v0[2], v1[2];
        const int kp = tid & 63;
        #pragma unroll
        for (int q2 = 0; q2 < 2; ++q2) {
            const int oc = (tid >> 6) + 4 * q2;
            const unsigned short* vg = QKV + ((size_t)(b * LSEQ + kz0 + 2 * kp)) * 3072
                                     + 2048 + h * 64 + oc * 8;
            v0[q2] = *(const bf16x8*)vg;
            v1[q2] = *(const bf16x8*)(vg + 3072);
        }
        #pragma unroll
        for (int q2 = 0; q2 < 2; ++q2) {
            const int oc = (tid >> 6) + 4 * q2;
            #pragma unroll
            for (int jj = 0; jj < 8; ++jj) {
                const unsigned int pk = (unsigned int)(unsigned short)v0[q2][jj]
                                      | ((unsigned int)(unsigned short)v1[q2][jj] << 16);
                *(unsigned int*)&Vt[(oc * 8 + jj) * 136 + 2 * kp] = pk;
            }
        }
        __syncthreads();                                   // B2: staging visible

        // ---- S = K·Q^T (per wave 64 keys x 64 queries) ----
        f32x4 acc_s[4][4];
        #pragma unroll
        for (int i = 0; i < 4; ++i)
            #pragma unroll
            for (int j = 0; j < 4; ++j) acc_s[i][j] = (f32x4){0.f, 0.f, 0.f, 0.f};
        #pragma unroll
        for (int kc = 0; kc < 2; ++kc) {
            bf16x8 kf[4], qf[4];
            #pragma unroll
            for (int i = 0; i < 4; ++i) {
                const int row = wm + i * 16 + fr;
                kf[i] = *(const bf16x8*)(Kls + row * 64 + (((kc * 4 + g) ^ (row & 7)) << 3));
            }
            #pragma unroll
            for (int j = 0; j < 4; ++j) {
                const int row = wn + j * 16 + fr;
                qf[j] = *(const bf16x8*)(Qls + row * 64 + (((kc * 4 + g) ^ (row & 7)) << 3));
            }
            #pragma unroll
            for (int i = 0; i < 4; ++i)
                #pragma unroll
                for (int j = 0; j < 4; ++j)
                    acc_s[i][j] = __builtin_amdgcn_mfma_f32_16x16x32_bf16(kf[i], qf[j], acc_s[i][j], 0, 0, 0);
        }

        // ---- scale + mask + per-query tile max ----
        float tmax[4];
        #pragma unroll
        for (int j = 0; j < 4; ++j) tmax[j] = -INFINITY;
        #pragma unroll
        for (int i = 0; i < 4; ++i)
            #pragma unroll
            for (int j = 0; j < 4; ++j)
                #pragma unroll
                for (int r = 0; r < 4; ++r) {
                    float s = acc_s[i][j][r] * 0.125f;
                    if (causal) {
                        const int key = kz0 + wm + i * 16 + 4 * g + r;
                        const int qq  = q0 + wn + j * 16 + fr;
                        if (key > qq) s = -INFINITY;
                    }
                    acc_s[i][j][r] = s;
                    tmax[j] = fmaxf(tmax[j], s);
                }
        #pragma unroll
        for (int j = 0; j < 4; ++j) {
            float v = tmax[j];
            v = fmaxf(v, __shfl_xor(v, 16));
            v = fmaxf(v, __shfl_xor(v, 32));
            tmax[j] = v;
        }
        if (lane < 16)
            #pragma unroll
            for (int j = 0; j < 4; ++j) redm[wv][j * 16 + fr] = tmax[j];
        __syncthreads();                                   // B3: partner max visible
        float mnew[4], tsum[4];
        #pragma unroll
        for (int j = 0; j < 4; ++j) {
            tmax[j] = fmaxf(tmax[j], redm[wv ^ 1][j * 16 + fr]);
            mnew[j] = fmaxf(m_run[j], tmax[j]);
            tsum[j] = 0.0f;
        }
        #pragma unroll
        for (int i = 0; i < 4; ++i)
            #pragma unroll
            for (int j = 0; j < 4; ++j)
                #pragma unroll
                for (int r = 0; r < 4; ++r) {
                    const float p = __expf(acc_s[i][j][r] - mnew[j]);
                    acc_s[i][j][r] = p;
                    tsum[j] += p;
                }
        #pragma unroll
        for (int j = 0; j < 4; ++j) {
            float v = tsum[j];
            v += __shfl_xor(v, 16);
            v += __shfl_xor(v, 32);
            tsum[j] = v;
        }
        if (lane < 16)
            #pragma unroll
            for (int j = 0; j < 4; ++j) reds[wv][j * 16 + fr] = tsum[j];
        __syncthreads();                                   // B4: partner sum visible
        float ef[4];
        #pragma unroll
        for (int j = 0; j < 4; ++j) {
            tsum[j] += reds[wv ^ 1][j * 16 + fr];
            ef[j] = __expf(m_run[j] - mnew[j]);
            l_run[j] = l_run[j] * ef[j] + tsum[j];
            m_run[j] = mnew[j];
        }
        if ((wv & 1) == 0 && lane < 16)
            #pragma unroll
            for (int j = 0; j < 4; ++j) scl[wn + j * 16 + fr] = ef[j];
        // ---- write P (bf16) to Pq[q][k] (r spans 4 consecutive k -> one b64) ----
        #pragma unroll
        for (int i = 0; i < 4; ++i)
            #pragma unroll
            for (int j = 0; j < 4; ++j) {
                short4 pk;
                pk.x = (short)f2bf(acc_s[i][j][0]);
                pk.y = (short)f2bf(acc_s[i][j][1]);
                pk.z = (short)f2bf(acc_s[i][j][2]);
                pk.w = (short)f2bf(acc_s[i][j][3]);
                *(short4*)&Pq[(wn + j * 16 + fr) * 136 + wm + i * 16 + 4 * g] = pk;
            }
        __syncthreads();                                   // B5: P + scl visible

        // ---- O rescale + PV (wave owns 32 q rows x 64 d) ----
        float f0[2][4];
        #pragma unroll
        for (int i = 0; i < 2; ++i)
            #pragma unroll
            for (int r = 0; r < 4; ++r) f0[i][r] = scl[32 * wv + 16 * i + 4 * g + r];
        #pragma unroll
        for (int i = 0; i < 2; ++i)
            #pragma unroll
            for (int j = 0; j < 4; ++j)
                #pragma unroll
                for (int r = 0; r < 4; ++r) acc_o[i][j][r] *= f0[i][r];
        #pragma unroll
        for (int kc = 0; kc < 4; ++kc) {
            bf16x8 pa[2], vb[4];
            #pragma unroll
            for (int i = 0; i < 2; ++i)
                pa[i] = *(const bf16x8*)(Pq + (32 * wv + 16 * i + fr) * 136 + kc * 32 + 8 * g);
            #pragma unroll
            for (int j = 0; j < 4; ++j)
                vb[j] = *(const bf16x8*)(Vt + (16 * j + fr) * 136 + kc * 32 + 8 * g);
            #pragma unroll
            for (int i = 0; i < 2; ++i)
                #pragma unroll
                for (int j = 0; j < 4; ++j)
                    acc_o[i][j] = __builtin_amdgcn_mfma_f32_16x16x32_bf16(pa[i], vb[j], acc_o[i][j], 0, 0, 0);
        }
    }

    // ---- epilogue: O /= l, store bf16 ----
    __syncthreads();
    if ((wv & 1) == 0 && lane < 16)
        #pragma unroll
        for (int j = 0; j < 4; ++j) scl[wn + j * 16 + fr] = 1.0f / l_run[j];
    __syncthreads();
    #pragma unroll
    for (int i = 0; i < 2; ++i) {
        #pragma unroll
        for (int r = 0; r < 4; ++r) {
            const int q  = q0 + 32 * wv + 16 * i + 4 * g + r;
            const float fl = scl[32 * wv + 16 * i + 4 * g + r];
            #pragma unroll
            for (int j = 0; j < 4; ++j) {
                const int d = 16 * j + fr;
                Ctx[((size_t)(b * LSEQ + q)) * DE + h * 64 + d] = f2bf(acc_o[i][j][r] * fl);
            }
        }
    }
}

// -------------------- layernorm over DE (ddof=1): fp32 in -> fp32 + bf16 out --------------------
__global__ __launch_bounds__(256)
void ln_kernel(const float* __restrict__ in, float* __restrict__ outf,
               unsigned short* __restrict__ outb,
               const float* __restrict__ g, const float* __restrict__ bb)
{
    __shared__ float red[256];
    const int tk  = blockIdx.x;
    const int tid = threadIdx.x;
    const float* xr = in + (size_t)tk * DE;
    const int d = tid * 4;
    float4 v = *(const float4*)(xr + d);

    red[tid] = v.x + v.y + v.z + v.w; __syncthreads();
    for (int st = 128; st > 0; st >>= 1) {
        if (tid < st) red[tid] += red[tid + st];
        __syncthreads();
    }
    const float mean = red[0] * (1.0f / DE);
    __syncthreads();

    float dx = v.x - mean, dy = v.y - mean, dz = v.z - mean, dw = v.w - mean;
    red[tid] = dx * dx + dy * dy + dz * dz + dw * dw;
    __syncthreads();
    for (int st = 128; st > 0; st >>= 1) {
        if (tid < st) red[tid] += red[tid + st];
        __syncthreads();
    }
    const float rstd = rsqrtf(red[0] * (1.0f / (DE - 1)) + EPSF);   // ddof=1

    float4 gg = *(const float4*)(g + d);
    float4 b4 = *(const float4*)(bb + d);
    float4 r;
    r.x = dx * rstd * gg.x + b4.x;
    r.y = dy * rstd * gg.y + b4.y;
    r.z = dz * rstd * gg.z + b4.z;
    r.w = dw * rstd * gg.w + b4.w;
    *(float4*)(outf + (size_t)tk * DE + d) = r;
    ushort4 rb; rb.x = f2bf(r.x); rb.y = f2bf(r.y); rb.z = f2bf(r.z); rb.w = f2bf(r.w);
    *(ushort4*)(outb + (size_t)tk * DE + d) = rb;
}

// -------------------- vocab softmax: pass2 (combine partials) + pass3 (normalize) ---------------
__global__ __launch_bounds__(256)
void vsm_pass2(const float* __restrict__ Pm, const float* __restrict__ Ps,
               float* __restrict__ Fm, float* __restrict__ Fr)
{
    const int tk = blockIdx.x * 256 + threadIdx.x;
    float M = -1e30f;
    for (int i = 0; i < NVT; ++i) M = fmaxf(M, Pm[(size_t)i * TOK + tk]);
    float S = 0.0f;
    for (int i = 0; i < NVT; ++i) S += Ps[(size_t)i * TOK + tk] * __expf(Pm[(size_t)i * TOK + tk] - M);
    Fm[tk] = M; Fr[tk] = 1.0f / S;
}

__global__ __launch_bounds__(256)
void vsm_pass3(float* __restrict__ out, const float* __restrict__ Fm, const float* __restrict__ Fr)
{
    const int tid = threadIdx.x, tx = tid & 63, ty = tid >> 6;
    const int l = blockIdx.x * 64 + tx, b = blockIdx.z;
    const int tk = b * LSEQ + l;
    const float M = Fm[tk], R = Fr[tk];
    const size_t base = ((size_t)b * NV + (size_t)blockIdx.y * 256) * LSEQ + l;
    for (int v = ty; v < 256; v += 4) {
        const size_t off = base + (size_t)v * LSEQ;
        out[off] = __expf(out[off] - M) * R;
    }
}

// ================================================================================================
extern "C" void kernel_launch(void* const* d_in, const int* in_sizes, int n_in,
                              void* d_out, int out_size, void* d_ws, size_t ws_size,
                              hipStream_t stream)
{
    (void)in_sizes; (void)n_in; (void)out_size; (void)ws_size;
    const int*   x  = (const int*)d_in[0];
    const int*   z  = (const int*)d_in[1];
    const float* We = (const float*)d_in[2];
    const float* Wp = (const float*)d_in[3];
    const float* Wu = (const float*)d_in[4];
    const float* encW[12]; for (int i = 0; i < 12; ++i) encW[i] = (const float*)d_in[5 + i];
    const float* encLN[4]; for (int i = 0; i < 4;  ++i) encLN[i] = (const float*)d_in[17 + i];
    const float* decW[12]; for (int i = 0; i < 12; ++i) decW[i] = (const float*)d_in[21 + i];
    const float* decLN[6]; for (int i = 0; i < 6;  ++i) decLN[i] = (const float*)d_in[33 + i];
    float* out = (float*)d_out;

    const size_t MB = 1024 * 1024;
    char* w = (char*)d_ws;
    float* Z            = (float*)(w + 0 * MB);          // 8 MB (reused for softmax partials)
    float* X            = (float*)(w + 8 * MB);          // 8 MB
    float* T            = (float*)(w + 16 * MB);         // 8 MB
    unsigned short* Zb  = (unsigned short*)(w + 24 * MB); // 4 MB
    unsigned short* Xb  = (unsigned short*)(w + 28 * MB); // 4 MB
    unsigned short* QKVb= (unsigned short*)(w + 32 * MB); // 12 MB (2048 x 3072)
    unsigned short* Cxb = (unsigned short*)(w + 44 * MB); // 4 MB
    unsigned short* Hb  = (unsigned short*)(w + 48 * MB); // 16 MB (2048 x 4096)
    unsigned short* Wqkvb = (unsigned short*)(w + 64 * MB); // 6 MB (3072 x 1024)
    unsigned short* Wob   = (unsigned short*)(w + 70 * MB); // 2 MB
    unsigned short* W1b   = (unsigned short*)(w + 72 * MB); // 8 MB
    unsigned short* W2b   = (unsigned short*)(w + 80 * MB); // 8 MB  -> 88 MB total
    float* pb = (float*)Hb;            // packed qkv bias; aliases Hb (dead until MLP1 writes it)
    // softmax partials alias Z (dead after decoder loop): Pm/Ps are [NVT][TOK]
    float* Pm = Z;                                        // 2 MB
    float* Ps = Z + (size_t)NVT * TOK;                    // 2 MB
    float* Fm = Z + (size_t)2 * NVT * TOK;                // 8 KB
    float* Fr = Fm + TOK;

    auto conv = [&](const float* s, unsigned short* d, int n) {
        convert_kernel<<<n / 1024, 256, 0, stream>>>(s, d);
    };
    auto conv3 = [&](const float* s0, const float* s1, const float* s2, unsigned short* d) {
        convert3_kernel<<<3 * DE * DE / 1024, 256, 0, stream>>>(s0, s1, s2, d);
    };
    auto gemm = [&](const unsigned short* A, const unsigned short* Wt, const float* bias,
                    const float* resid, float* Cf, unsigned short* Cb, int ldC, int ntiles,
                    int K, int relu) {
        gemm_bf16<<<dim3(TOK / 128, ntiles), 256, 0, stream>>>(A, Wt, bias, resid, Cf, Cb,
                                                               ldC, K, relu);
    };
    auto lnorm = [&](const float* in, float* of, unsigned short* ob,
                     const float* g, const float* bb) {
        ln_kernel<<<TOK, 256, 0, stream>>>(in, of, ob, g, bb);
    };
    auto attn = [&](unsigned short* ctx, int causal) {
        attn_kernel<<<dim3(LSEQ / 128, NH, B_), 256, 0, stream>>>(QKVb, ctx, causal);
    };

    // ---------------- encoder ----------------
    embed_kernel<<<TOK, 256, 0, stream>>>(z, We, Wp, Z, Zb);
    for (int l = 0; l < 2; ++l) {
        const size_t wo  = (size_t)l * DE * DE;
        const size_t bo  = (size_t)l * DE;
        const size_t w1o = (size_t)l * DMLP * DE;
        const size_t b1o = (size_t)l * DMLP;
        conv3(encW[0] + wo, encW[2] + wo, encW[4] + wo, Wqkvb);
        pack_qkv_bias<<<12, 256, 0, stream>>>(encW[1] + bo, encW[3] + bo, encW[5] + bo, pb);
        gemm(Zb, Wqkvb, pb, nullptr, nullptr, QKVb, 3072, 24, DE, 0);
        attn(Cxb, 0);
        conv(encW[6] + wo, Wob, DE * DE);
        gemm(Cxb, Wob, encW[7] + bo, Z, T, nullptr, DE, 8, DE, 0);
        lnorm(T, Z, Zb, encLN[0] + bo, encLN[1] + bo);
        conv(encW[8] + w1o, W1b, DMLP * DE);
        gemm(Zb, W1b, encW[9] + b1o, nullptr, nullptr, Hb, DMLP, 32, DE, 1);
        conv(encW[10] + w1o, W2b, DMLP * DE);
        gemm(Hb, W2b, encW[11] + bo, Z, T, nullptr, DE, 8, DMLP, 0);
        lnorm(T, Z, Zb, encLN[2] + bo, encLN[3] + bo);
    }

    // ---------------- decoder ----------------
    embed_kernel<<<TOK, 256, 0, stream>>>(x, We, Wp, X, Xb);
    for (int l = 0; l < 2; ++l) {
        const size_t wo  = (size_t)l * DE * DE;
        const size_t bo  = (size_t)l * DE;
        const size_t w1o = (size_t)l * DMLP * DE;
        const size_t b1o = (size_t)l * DMLP;
        conv3(decW[0] + wo, decW[2] + wo, decW[4] + wo, Wqkvb);
        pack_qkv_bias<<<12, 256, 0, stream>>>(decW[1] + bo, decW[3] + bo, decW[5] + bo, pb);
        conv(decW[6] + wo, Wob, DE * DE);
        // self-attention (causal)
        gemm(Xb, Wqkvb, pb, nullptr, nullptr, QKVb, 3072, 24, DE, 0);
        attn(Cxb, 1);
        gemm(Cxb, Wob, decW[7] + bo, X, T, nullptr, DE, 8, DE, 0);
        lnorm(T, X, Xb, decLN[0] + bo, decLN[1] + bo);
        // cross-attention: Q from X, K/V from encoder Z (same weights)
        gemm(Xb, Wqkvb, pb, nullptr, nullptr, QKVb, 3072, 8, DE, 0);                     // Q
        gemm(Zb, Wqkvb + DE * DE, pb + 1024, nullptr, nullptr, QKVb + 1024, 3072, 16, DE, 0); // K,V
        attn(Cxb, 0);
        gemm(Cxb, Wob, decW[7] + bo, X, T, nullptr, DE, 8, DE, 0);
        lnorm(T, X, Xb, decLN[2] + bo, decLN[3] + bo);
        // MLP
        conv(decW[8] + w1o, W1b, DMLP * DE);
        gemm(Xb, W1b, decW[9] + b1o, nullptr, nullptr, Hb, DMLP, 32, DE, 1);
        conv(decW[10] + w1o, W2b, DMLP * DE);
        gemm(Hb, W2b, decW[11] + bo, X, T, nullptr, DE, 8, DMLP, 0);
        lnorm(T, X, Xb, decLN[4] + bo, decLN[5] + bo);
    }

    // ---------------- unembed (fused softmax pass1) + vocab softmax -------------------------
    unembed_kernel<<<dim3(TOK / 128, NVT), 256, 0, stream>>>(Wu, Xb, out, Pm, Ps);
    vsm_pass2<<<TOK / 256, 256, 0, stream>>>(Pm, Ps, Fm, Fr);
    vsm_pass3<<<dim3(LSEQ / 64, NV / 256, B_), 256, 0, stream>>>(out, Fm, Fr);
}